// Round 8
// baseline (93.289 us; speedup 1.0000x reference)
//
#include <hip/hip_runtime.h>

// Problem constants (fixed by the reference)
constexpr int BN  = 64;          // batch
constexpr int HWP = 784;         // 28*28 spatial positions
constexpr int CQ  = 256;         // 1024 channels / 4 = float4s per position
constexpr float TAU = 0.5f / 784.0f;
constexpr float MS  = -(TAU / 7.0f);   // -beta*tau/n = -4*tau/28

// Native clang vector type (required by __builtin_nontemporal_store).
typedef float f32x4 __attribute__((ext_vector_type(4)));

__device__ __forceinline__ int iabs(int x) { return x < 0 ? -x : x; }

// ---------------------------------------------------------------------------
// Wave-autonomous fused kernel — ZERO barriers, zero LDS.
// One wave owns one (batch b, 32-channel group cg) tile (2048 waves total).
// Lane: q = lane&7 (channel quad), s = lane>>3 (position sub-lane 0..7).
// Lane visits p = s + 8k, k = 0..97. A wave-load covers 8 positions x 128 B
// = 1 KB CONTIGUOUS (8 full L2 lines owned by one wave — round 5 showed
// splitting lines across consumers doubles FETCH).
//
// Pass A: per-lane argmax (ascending p, strict '>' = first occurrence).
// Reduce: 3-stage shfl_xor butterfly over lane bits 3..5 (the 8 position
//   sub-lanes) with (v > bv) || (v == bv && x < bx) tie-break -> exact
//   jnp.argmax semantics. Afterwards EVERY lane holds the argmax for its own
//   4 channels — no broadcast needed. No __syncthreads anywhere: waves drift
//   independently, so memory pipes never drain (rounds 4-7: the block-wide
//   barrier phase-lock was the ~30% loss; compiler refused to hold registers
//   across it — VGPR=64 r7, VGPR=36 r4).
// Pass C: re-read the tile (hot in L2/L3 — rounds 4/6: re-read adds no HBM
//   FETCH), apply mask, nontemporal store (keeps input L3-resident).
//   Inner unroll of 7: 7*8 = 56 = 2 rows, so per-slot j is compile-time
//   constant -> per-channel dj hoisted by the compiler.
// Mask: tau * max(1 - 4d/28, -1) == max(fma(d, -tau/7, tau), -tau)
// (~2 ulp of tau; measured absmax 7.6e-6 vs threshold 6.9e-5).
// ---------------------------------------------------------------------------
__global__ __launch_bounds__(256) void fused_wave_kernel(
    const f32x4* __restrict__ in4, f32x4* __restrict__ out4) {
  const int t    = threadIdx.x;
  const int lane = t & 63;
  const int wv   = t >> 6;                 // wave within block (independent)
  const int q    = lane & 7;               // channel quad
  const int s    = lane >> 3;              // position sub-lane 0..7
  const int gw   = blockIdx.x * 4 + wv;    // global wave id 0..2047
  const int b    = gw >> 5;                // batch
  const int cg   = gw & 31;                // 32-channel group

  const size_t base = ((size_t)b * HWP + s) * CQ + cg * 8 + q;
  const f32x4* sp = in4 + base;
  f32x4*       dp = out4 + base;
  constexpr size_t PSTR = (size_t)8 * CQ;  // advance 8 positions

  // ---- Pass A: per-lane argmax over p = s + 8k, k = 0..97 ----
  float bm0 = -__builtin_inff(), bm1 = bm0, bm2 = bm0, bm3 = bm0;
  int   bi0 = s, bi1 = s, bi2 = s, bi3 = s;
  for (int g = 0; g < 14; ++g) {
    #pragma unroll
    for (int u = 0; u < 7; ++u) {          // 7 loads in flight per iteration
      const int k = g * 7 + u;
      const f32x4 v = sp[(size_t)k * PSTR];
      const int p = s + 8 * k;
      if (v.x > bm0) { bm0 = v.x; bi0 = p; }
      if (v.y > bm1) { bm1 = v.y; bi1 = p; }
      if (v.z > bm2) { bm2 = v.z; bi2 = p; }
      if (v.w > bm3) { bm3 = v.w; bi3 = p; }
    }
  }

  // ---- Butterfly reduce across the 8 position sub-lanes (no LDS) ----
  #pragma unroll
  for (int st = 8; st < 64; st <<= 1) {
    { const float ov = __shfl_xor(bm0, st, 64); const int ox = __shfl_xor(bi0, st, 64);
      if (ov > bm0 || (ov == bm0 && ox < bi0)) { bm0 = ov; bi0 = ox; } }
    { const float ov = __shfl_xor(bm1, st, 64); const int ox = __shfl_xor(bi1, st, 64);
      if (ov > bm1 || (ov == bm1 && ox < bi1)) { bm1 = ov; bi1 = ox; } }
    { const float ov = __shfl_xor(bm2, st, 64); const int ox = __shfl_xor(bi2, st, 64);
      if (ov > bm2 || (ov == bm2 && ox < bi2)) { bm2 = ov; bi2 = ox; } }
    { const float ov = __shfl_xor(bm3, st, 64); const int ox = __shfl_xor(bi3, st, 64);
      if (ov > bm3 || (ov == bm3 && ox < bi3)) { bm3 = ov; bi3 = ox; } }
  }

  const int im0 = bi0 / 28, jm0 = bi0 - 28 * im0;
  const int im1 = bi1 / 28, jm1 = bi1 - 28 * im1;
  const int im2 = bi2 / 28, jm2 = bi2 - 28 * im2;
  const int im3 = bi3 / 28, jm3 = bi3 - 28 * im3;

  // ---- Pass C: re-read (L2/L3-hot), mask, nontemporal store ----
  for (int g = 0; g < 14; ++g) {
    #pragma unroll
    for (int u = 0; u < 7; ++u) {
      const int k  = g * 7 + u;
      const int su = s + 8 * u;            // < 56: spans exactly 2 rows
      const int iU = su / 28;              // compile-time per slot u
      const int jU = su - 28 * iU;         // compile-time per slot u
      const int i  = 2 * g + iU;
      const f32x4 v = sp[(size_t)k * PSTR];
      f32x4 o;
      o.x = v.x * fmaxf(fmaf((float)(iabs(i - im0) + iabs(jU - jm0)), MS, TAU), -TAU);
      o.y = v.y * fmaxf(fmaf((float)(iabs(i - im1) + iabs(jU - jm1)), MS, TAU), -TAU);
      o.z = v.z * fmaxf(fmaf((float)(iabs(i - im2) + iabs(jU - jm2)), MS, TAU), -TAU);
      o.w = v.w * fmaxf(fmaf((float)(iabs(i - im3) + iabs(jU - jm3)), MS, TAU), -TAU);
      __builtin_nontemporal_store(o, dp + (size_t)k * PSTR);
    }
  }
}

extern "C" void kernel_launch(void* const* d_in, const int* in_sizes, int n_in,
                              void* d_out, int out_size, void* d_ws, size_t ws_size,
                              hipStream_t stream) {
  const f32x4* in4  = (const f32x4*)d_in[0];
  f32x4*       out4 = (f32x4*)d_out;
  // 2048 autonomous waves = 512 blocks x 256 threads (4 waves/block, no
  // inter-wave communication).
  fused_wave_kernel<<<512, 256, 0, stream>>>(in4, out4);
}

// Round 9
// 69.402 us; speedup vs baseline: 1.3442x; 1.3442x over previous
//
#include <hip/hip_runtime.h>

// Problem constants (fixed by the reference)
constexpr int HWP = 784;         // 28*28 spatial positions
constexpr int CQ  = 256;         // 1024 channels / 4 = float4s per position
constexpr float TAU = 0.5f / 784.0f;
constexpr float MS  = -(TAU / 7.0f);   // -beta*tau/n = -4*tau/28

// Native clang vector type (required by __builtin_nontemporal_store).
typedef float f32x4 __attribute__((ext_vector_type(4)));

__device__ __forceinline__ int iabs(int x) { return x < 0 ? -x : x; }

// ---------------------------------------------------------------------------
// Persistent fused kernel — round-4 tile shape, per-tile barriers, NO
// register prefetch, NO pinning (round 7's prefetch was sunk by the
// compiler; round 6 showed pinning buys nothing because pass-C re-reads are
// L2/L3 hits anyway).
//
// Grid: 512 blocks x 512 threads, 2 blocks/CU, ALL resident from t=0.
// Block bk owns batch b = bk>>3 and 4 consecutive 32-channel tiles
// cg = (bk&7)*4 .. +3. Thread: q = t&7 (channel quad -> wave covers 8 quads
// x 16 B = full 128 B line per position; round 5 proved line-splitting
// doubles FETCH), s3 = t>>3 (64 position splits); owns p = s3 + 64k,
// k = 0..11, +k=12 if s3<16 (waves 0-1, wave-uniform).
//
// Why persistent+per-tile barriers: round 4 = one tile per block, all blocks
// phase-locked as a global cohort (load-all / reduce-all / store-all ->
// measured 4.4 TB/s, the zero-overlap regime). Here tile n's stores and tile
// n+1's loads have NO barrier between them, so waves drift and the memory
// pipes stay busy across tile boundaries; the reduce stall is per-block.
// Per-XCD live set ~6 MB (vs round 8's 205 MB chip-wide thrash that doubled
// FETCH) keeps pass-C re-reads L2-hot and preserves cross-replay L3
// retention of the input (~50%, FETCH ~100 GB-units).
//
// Reduce: shfl_xor butterfly over the wave's 8 position-splits with
// (v > bv) || (v == bv && x < bx) tie-break, then 8 wave-partials x 32
// channels through 2.6 KB LDS. Exact jnp.argmax first-occurrence semantics
// (ascending p, strict '>' within a lane; min-index on value ties across
// lanes/waves).
// LDS cross-tile safety: wave X can only write s2v for tile n+1 after
// passing tile n's second barrier, which requires wave 0 to have finished
// reading s2v/s_peak for tile n (and vice versa for s_peak) — no hazard.
// Mask: tau * max(1 - 4d/28, -1) == max(fma(d, -tau/7, tau), -tau)
// (~2 ulp of tau; measured absmax 7.6e-6 vs threshold 6.9e-5).
// ---------------------------------------------------------------------------
__global__ __launch_bounds__(512, 4) void fused_persist_kernel(
    const f32x4* __restrict__ in4, f32x4* __restrict__ out4) {
  __shared__ float s2v[8][32];
  __shared__ int   s2i[8][32];
  __shared__ int   s_peak[32];

  const int t   = threadIdx.x;
  const int q   = t & 7;           // channel quad within the 32-ch tile
  const int s3  = t >> 3;          // position split 0..63
  const int w   = t >> 6;          // wave 0..7
  const int b   = blockIdx.x >> 3;
  const int cg0 = (blockIdx.x & 7) * 4;

  constexpr size_t KSTR = (size_t)64 * CQ;   // 64 positions per k-step
  const f32x4* sp = in4  + ((size_t)b * HWP + s3) * CQ + cg0 * 8 + q;
  f32x4*       dp = out4 + ((size_t)b * HWP + s3) * CQ + cg0 * 8 + q;

  const bool tail = (s3 < 16);     // wave-uniform (waves 0,1)
  const int  i0 = s3 / 28;
  const int  j0 = s3 - 28 * i0;
  const int  c0 = q * 4;

  for (int tile = 0; tile < 4; ++tile) {
    // ---- Phase A: 12(+1) loads, per-lane argmax ----
    f32x4 v[12];
    #pragma unroll
    for (int k = 0; k < 12; ++k) v[k] = sp[(size_t)k * KSTR];
    f32x4 vt = {0.0f, 0.0f, 0.0f, 0.0f};
    if (tail) vt = sp[(size_t)12 * KSTR];

    float bm0 = -__builtin_inff(), bm1 = bm0, bm2 = bm0, bm3 = bm0;
    int   bi0 = s3, bi1 = s3, bi2 = s3, bi3 = s3;
    #pragma unroll
    for (int k = 0; k < 12; ++k) {
      const int p = s3 + 64 * k;
      if (v[k].x > bm0) { bm0 = v[k].x; bi0 = p; }
      if (v[k].y > bm1) { bm1 = v[k].y; bi1 = p; }
      if (v[k].z > bm2) { bm2 = v[k].z; bi2 = p; }
      if (v[k].w > bm3) { bm3 = v[k].w; bi3 = p; }
    }
    if (tail) {
      const int p = s3 + 768;
      if (vt.x > bm0) { bm0 = vt.x; bi0 = p; }
      if (vt.y > bm1) { bm1 = vt.y; bi1 = p; }
      if (vt.z > bm2) { bm2 = vt.z; bi2 = p; }
      if (vt.w > bm3) { bm3 = vt.w; bi3 = p; }
    }

    // ---- In-wave butterfly over the 8 position sub-lanes ----
    #pragma unroll
    for (int st = 8; st < 64; st <<= 1) {
      { const float ov = __shfl_xor(bm0, st, 64); const int ox = __shfl_xor(bi0, st, 64);
        if (ov > bm0 || (ov == bm0 && ox < bi0)) { bm0 = ov; bi0 = ox; } }
      { const float ov = __shfl_xor(bm1, st, 64); const int ox = __shfl_xor(bi1, st, 64);
        if (ov > bm1 || (ov == bm1 && ox < bi1)) { bm1 = ov; bi1 = ox; } }
      { const float ov = __shfl_xor(bm2, st, 64); const int ox = __shfl_xor(bi2, st, 64);
        if (ov > bm2 || (ov == bm2 && ox < bi2)) { bm2 = ov; bi2 = ox; } }
      { const float ov = __shfl_xor(bm3, st, 64); const int ox = __shfl_xor(bi3, st, 64);
        if (ov > bm3 || (ov == bm3 && ox < bi3)) { bm3 = ov; bi3 = ox; } }
    }

    // ---- Cross-wave reduce via tiny LDS ----
    if ((t & 56) == 0) {           // one rep lane per (wave, quad)
      s2v[w][c0 + 0] = bm0; s2i[w][c0 + 0] = bi0;
      s2v[w][c0 + 1] = bm1; s2i[w][c0 + 1] = bi1;
      s2v[w][c0 + 2] = bm2; s2i[w][c0 + 2] = bi2;
      s2v[w][c0 + 3] = bm3; s2i[w][c0 + 3] = bi3;
    }
    __syncthreads();
    if (t < 32) {
      float bv = s2v[0][t];
      int   bx = s2i[0][t];
      #pragma unroll
      for (int g = 1; g < 8; ++g) {
        const float vv = s2v[g][t];
        const int   xx = s2i[g][t];
        if (vv > bv || (vv == bv && xx < bx)) { bv = vv; bx = xx; }
      }
      const int im = bx / 28;
      s_peak[t] = (im << 8) | (bx - 28 * im);
    }
    __syncthreads();

    // ---- Phase C: mask + nontemporal store ----
    const int pk0 = s_peak[c0 + 0], pk1 = s_peak[c0 + 1];
    const int pk2 = s_peak[c0 + 2], pk3 = s_peak[c0 + 3];
    const int im0 = pk0 >> 8, jm0 = pk0 & 255;
    const int im1 = pk1 >> 8, jm1 = pk1 & 255;
    const int im2 = pk2 >> 8, jm2 = pk2 & 255;
    const int im3 = pk3 >> 8, jm3 = pk3 & 255;

    int i = i0, j = j0;
    #pragma unroll
    for (int k = 0; k < 12; ++k) {
      f32x4 o;
      o.x = v[k].x * fmaxf(fmaf((float)(iabs(i - im0) + iabs(j - jm0)), MS, TAU), -TAU);
      o.y = v[k].y * fmaxf(fmaf((float)(iabs(i - im1) + iabs(j - jm1)), MS, TAU), -TAU);
      o.z = v[k].z * fmaxf(fmaf((float)(iabs(i - im2) + iabs(j - jm2)), MS, TAU), -TAU);
      o.w = v[k].w * fmaxf(fmaf((float)(iabs(i - im3) + iabs(j - jm3)), MS, TAU), -TAU);
      __builtin_nontemporal_store(o, dp + (size_t)k * KSTR);
      j += 8; i += 2; if (j >= 28) { j -= 28; ++i; }   // p += 64
    }
    if (tail) {
      f32x4 o;
      o.x = vt.x * fmaxf(fmaf((float)(iabs(i - im0) + iabs(j - jm0)), MS, TAU), -TAU);
      o.y = vt.y * fmaxf(fmaf((float)(iabs(i - im1) + iabs(j - jm1)), MS, TAU), -TAU);
      o.z = vt.z * fmaxf(fmaf((float)(iabs(i - im2) + iabs(j - jm2)), MS, TAU), -TAU);
      o.w = vt.w * fmaxf(fmaf((float)(iabs(i - im3) + iabs(j - jm3)), MS, TAU), -TAU);
      __builtin_nontemporal_store(o, dp + (size_t)12 * KSTR);
    }

    sp += 8; dp += 8;              // next 32-channel tile (consecutive)
  }
}

extern "C" void kernel_launch(void* const* d_in, const int* in_sizes, int n_in,
                              void* d_out, int out_size, void* d_ws, size_t ws_size,
                              hipStream_t stream) {
  const f32x4* in4  = (const f32x4*)d_in[0];
  f32x4*       out4 = (f32x4*)d_out;
  // 512 persistent blocks x 512 threads; each block does 4 consecutive
  // 32-channel tiles of one batch. 2 blocks/CU, all resident.
  fused_persist_kernel<<<512, 512, 0, stream>>>(in4, out4);
}

// Round 10
// 69.307 us; speedup vs baseline: 1.3460x; 1.0014x over previous
//
#include <hip/hip_runtime.h>

// Problem constants (fixed by the reference)
constexpr int HWP = 784;         // 28*28 spatial positions
constexpr int CQ  = 256;         // 1024 channels / 4 = float4s per position
constexpr float TAU = 0.5f / 784.0f;
constexpr float MS  = -(TAU / 7.0f);   // -beta*tau/n = -4*tau/28

// Native clang vector type (required by __builtin_nontemporal_store).
typedef float f32x4 __attribute__((ext_vector_type(4)));

__device__ __forceinline__ int iabs(int x) { return x < 0 ? -x : x; }

// ---------------------------------------------------------------------------
// Persistent fused kernel + FORCED register residency.
// Round-9 structure (512 blocks x 512 threads, 2 blocks/CU, block owns 4
// consecutive 32-channel tiles of one batch; per-tile barriers) with one
// change: the 13 loaded f32x4s are PINNED via asm "+v" after the argmax, so
// the compiler must carry them across the reduce barriers and pass C uses
// registers instead of re-loading.
//
// Why: round 9's VGPR=64 proved the v[] array was rematerialized — pass C
// re-read 205 MB through L2/L3 every call. Fabric accounting: 615 MB at
// 69.4 us = 8.9 TB/s fabric vs only 4.45 TB/s HBM. If fabric/L3 is the
// binding resource, cutting the re-read (fabric 615 -> 410 MB) is worth
// ~30%. Round 6 proved the pin itself works (VGPR=36=28data+8state) but
// was buried in a 14-wave phase-locked shape; this is pin + good shape.
//
// Thread: q = t&7 (8 quads x 16 B = full 128 B line per position; round 5
// proved line-splitting doubles FETCH), s3 = t>>3; owns p = s3 + 64k,
// k=0..11, +k=12 if s3<16 (waves 0-1, wave-uniform).
// Reduce: shfl_xor butterfly over the wave's 8 position-splits with
// (v > bv) || (v == bv && x < bx) tie-break, then 8 wave-partials x 32
// channels through 2.6 KB LDS -> exact jnp.argmax first-occurrence.
// LDS cross-tile safety: next tile's s2v writes only happen after this
// tile's second barrier (s2v readers done); s_peak writes only after the
// same barrier (s_peak readers of the previous tile done) — no hazard.
// Mask: tau * max(1 - 4d/28, -1) == max(fma(d, -tau/7, tau), -tau)
// (~2 ulp of tau; measured absmax 7.6e-6 vs threshold 6.9e-5).
// __launch_bounds__(512, 4): VGPR cap 128; data 52 + state ~44 fits.
// ---------------------------------------------------------------------------
__global__ __launch_bounds__(512, 4) void fused_persist_pin_kernel(
    const f32x4* __restrict__ in4, f32x4* __restrict__ out4) {
  __shared__ float s2v[8][32];
  __shared__ int   s2i[8][32];
  __shared__ int   s_peak[32];

  const int t   = threadIdx.x;
  const int q   = t & 7;           // channel quad within the 32-ch tile
  const int s3  = t >> 3;          // position split 0..63
  const int w   = t >> 6;          // wave 0..7
  const int b   = blockIdx.x >> 3;
  const int cg0 = (blockIdx.x & 7) * 4;

  constexpr size_t KSTR = (size_t)64 * CQ;   // 64 positions per k-step
  const f32x4* sp = in4  + ((size_t)b * HWP + s3) * CQ + cg0 * 8 + q;
  f32x4*       dp = out4 + ((size_t)b * HWP + s3) * CQ + cg0 * 8 + q;

  const bool tail = (s3 < 16);     // wave-uniform (waves 0,1)
  const int  i0 = s3 / 28;
  const int  j0 = s3 - 28 * i0;
  const int  c0 = q * 4;

#define AMAX(vv, k) { const int p = s3 + 64 * (k); \
    if (vv.x > bm0) { bm0 = vv.x; bi0 = p; } \
    if (vv.y > bm1) { bm1 = vv.y; bi1 = p; } \
    if (vv.z > bm2) { bm2 = vv.z; bi2 = p; } \
    if (vv.w > bm3) { bm3 = vv.w; bi3 = p; } }

#define APK(vv, off) { f32x4 o; \
    o.x = vv.x * fmaxf(fmaf((float)(iabs(i - im0) + iabs(j - jm0)), MS, TAU), -TAU); \
    o.y = vv.y * fmaxf(fmaf((float)(iabs(i - im1) + iabs(j - jm1)), MS, TAU), -TAU); \
    o.z = vv.z * fmaxf(fmaf((float)(iabs(i - im2) + iabs(j - jm2)), MS, TAU), -TAU); \
    o.w = vv.w * fmaxf(fmaf((float)(iabs(i - im3) + iabs(j - jm3)), MS, TAU), -TAU); \
    __builtin_nontemporal_store(o, dp + (off)); \
    j += 8; i += 2; if (j >= 28) { j -= 28; ++i; } }   // p += 64

  for (int tile = 0; tile < 4; ++tile) {
    // ---- Phase A: 12(+1) loads into NAMED registers, per-lane argmax ----
    f32x4 v0  = sp[ 0 * KSTR], v1  = sp[ 1 * KSTR], v2  = sp[ 2 * KSTR];
    f32x4 v3  = sp[ 3 * KSTR], v4  = sp[ 4 * KSTR], v5  = sp[ 5 * KSTR];
    f32x4 v6  = sp[ 6 * KSTR], v7  = sp[ 7 * KSTR], v8  = sp[ 8 * KSTR];
    f32x4 v9  = sp[ 9 * KSTR], v10 = sp[10 * KSTR], v11 = sp[11 * KSTR];
    f32x4 vt  = {0.0f, 0.0f, 0.0f, 0.0f};
    if (tail) vt = sp[(size_t)12 * KSTR];

    float bm0 = -__builtin_inff(), bm1 = bm0, bm2 = bm0, bm3 = bm0;
    int   bi0 = s3, bi1 = s3, bi2 = s3, bi3 = s3;
    AMAX(v0, 0)  AMAX(v1, 1)  AMAX(v2, 2)  AMAX(v3, 3)
    AMAX(v4, 4)  AMAX(v5, 5)  AMAX(v6, 6)  AMAX(v7, 7)
    AMAX(v8, 8)  AMAX(v9, 9)  AMAX(v10, 10) AMAX(v11, 11)
    if (tail) {
      const int p = s3 + 768;
      if (vt.x > bm0) { bm0 = vt.x; bi0 = p; }
      if (vt.y > bm1) { bm1 = vt.y; bi1 = p; }
      if (vt.z > bm2) { bm2 = vt.z; bi2 = p; }
      if (vt.w > bm3) { bm3 = vt.w; bi3 = p; }
    }

    // ---- PIN: values must live in VGPRs past the barriers (no re-load) ----
    asm volatile("" : "+v"(v0), "+v"(v1), "+v"(v2), "+v"(v3),
                      "+v"(v4), "+v"(v5), "+v"(v6), "+v"(v7),
                      "+v"(v8), "+v"(v9), "+v"(v10), "+v"(v11), "+v"(vt));

    // ---- In-wave butterfly over the 8 position sub-lanes ----
    #pragma unroll
    for (int st = 8; st < 64; st <<= 1) {
      { const float ov = __shfl_xor(bm0, st, 64); const int ox = __shfl_xor(bi0, st, 64);
        if (ov > bm0 || (ov == bm0 && ox < bi0)) { bm0 = ov; bi0 = ox; } }
      { const float ov = __shfl_xor(bm1, st, 64); const int ox = __shfl_xor(bi1, st, 64);
        if (ov > bm1 || (ov == bm1 && ox < bi1)) { bm1 = ov; bi1 = ox; } }
      { const float ov = __shfl_xor(bm2, st, 64); const int ox = __shfl_xor(bi2, st, 64);
        if (ov > bm2 || (ov == bm2 && ox < bi2)) { bm2 = ov; bi2 = ox; } }
      { const float ov = __shfl_xor(bm3, st, 64); const int ox = __shfl_xor(bi3, st, 64);
        if (ov > bm3 || (ov == bm3 && ox < bi3)) { bm3 = ov; bi3 = ox; } }
    }

    // ---- Cross-wave reduce via tiny LDS ----
    if ((t & 56) == 0) {             // one rep lane per (wave, quad)
      s2v[w][c0 + 0] = bm0; s2i[w][c0 + 0] = bi0;
      s2v[w][c0 + 1] = bm1; s2i[w][c0 + 1] = bi1;
      s2v[w][c0 + 2] = bm2; s2i[w][c0 + 2] = bi2;
      s2v[w][c0 + 3] = bm3; s2i[w][c0 + 3] = bi3;
    }
    __syncthreads();
    if (t < 32) {
      float bv = s2v[0][t];
      int   bx = s2i[0][t];
      #pragma unroll
      for (int g = 1; g < 8; ++g) {
        const float vv = s2v[g][t];
        const int   xx = s2i[g][t];
        if (vv > bv || (vv == bv && xx < bx)) { bv = vv; bx = xx; }
      }
      const int im = bx / 28;
      s_peak[t] = (im << 8) | (bx - 28 * im);
    }
    __syncthreads();

    // ---- Phase C: mask the register-resident values, nontemporal store ----
    const int pk0 = s_peak[c0 + 0], pk1 = s_peak[c0 + 1];
    const int pk2 = s_peak[c0 + 2], pk3 = s_peak[c0 + 3];
    const int im0 = pk0 >> 8, jm0 = pk0 & 255;
    const int im1 = pk1 >> 8, jm1 = pk1 & 255;
    const int im2 = pk2 >> 8, jm2 = pk2 & 255;
    const int im3 = pk3 >> 8, jm3 = pk3 & 255;

    int i = i0, j = j0;
    APK(v0,  0 * KSTR) APK(v1,  1 * KSTR) APK(v2,  2 * KSTR)
    APK(v3,  3 * KSTR) APK(v4,  4 * KSTR) APK(v5,  5 * KSTR)
    APK(v6,  6 * KSTR) APK(v7,  7 * KSTR) APK(v8,  8 * KSTR)
    APK(v9,  9 * KSTR) APK(v10, 10 * KSTR) APK(v11, 11 * KSTR)
    if (tail) {
      f32x4 o;
      o.x = vt.x * fmaxf(fmaf((float)(iabs(i - im0) + iabs(j - jm0)), MS, TAU), -TAU);
      o.y = vt.y * fmaxf(fmaf((float)(iabs(i - im1) + iabs(j - jm1)), MS, TAU), -TAU);
      o.z = vt.z * fmaxf(fmaf((float)(iabs(i - im2) + iabs(j - jm2)), MS, TAU), -TAU);
      o.w = vt.w * fmaxf(fmaf((float)(iabs(i - im3) + iabs(j - jm3)), MS, TAU), -TAU);
      __builtin_nontemporal_store(o, dp + (size_t)12 * KSTR);
    }

    sp += 8; dp += 8;                // next 32-channel tile (consecutive)
  }
#undef APK
#undef AMAX
}

extern "C" void kernel_launch(void* const* d_in, const int* in_sizes, int n_in,
                              void* d_out, int out_size, void* d_ws, size_t ws_size,
                              hipStream_t stream) {
  const f32x4* in4  = (const f32x4*)d_in[0];
  f32x4*       out4 = (f32x4*)d_out;
  // 512 persistent blocks x 512 threads; each block does 4 consecutive
  // 32-channel tiles of one batch. 2 blocks/CU, all resident.
  fused_persist_pin_kernel<<<512, 512, 0, stream>>>(in4, out4);
}